// Round 2
// baseline (1370.931 us; speedup 1.0000x reference)
//
#include <hip/hip_runtime.h>
#include <hip/hip_bf16.h>

#define N_POL  50000
#define N_TICK 200000
#define N_COMM 5000
#define N_NODES 255000   // N_POL + N_TICK + N_COMM
#define N_EDGES 4000000
#define EMB 32
#define HID 64
#define OUT_D 32

// ---------------------------------------------------------------------------
// K1: fused node embedding + layernorm.  One 32-lane group per node row.
// ---------------------------------------------------------------------------
__global__ __launch_bounds__(256) void k_embed(
    const float* __restrict__ pol_features, const int* __restrict__ state_ids,
    const int* __restrict__ sector_ids, const int* __restrict__ industry_ids,
    const float* __restrict__ comp_extra,
    const float* __restrict__ pol_W, const float* __restrict__ pol_b,
    const float* __restrict__ state_emb, const float* __restrict__ sector_emb,
    const float* __restrict__ industry_emb, const float* __restrict__ comp_W,
    const float* __restrict__ comp_b, const float* __restrict__ comm_emb,
    const float* __restrict__ ln_g, const float* __restrict__ ln_b,
    float* __restrict__ x)
{
    int tid = blockIdx.x * 256 + threadIdx.x;
    int r = tid >> 5;
    int c = tid & 31;
    if (r >= N_NODES) return;

    float acc;
    if (r < N_POL) {
        acc = pol_b[c];
        #pragma unroll
        for (int k = 0; k < 7; ++k)
            acc = fmaf(pol_features[r*7 + k], pol_W[k*EMB + c], acc);
        acc = fmaxf(acc, 0.f);
        acc += state_emb[state_ids[r]*EMB + c];
    } else if (r < N_POL + N_TICK) {
        int i = r - N_POL;
        acc = comp_b[c];
        int sec = sector_ids[i], ind = industry_ids[i];
        #pragma unroll
        for (int k = 0; k < 8; ++k)
            acc = fmaf(sector_emb[sec*8 + k], comp_W[k*EMB + c], acc);
        #pragma unroll
        for (int k = 0; k < 8; ++k)
            acc = fmaf(industry_emb[ind*8 + k], comp_W[(8+k)*EMB + c], acc);
        acc = fmaf(comp_extra[i], comp_W[16*EMB + c], acc);
        acc = fmaxf(acc, 0.f);
    } else {
        acc = comm_emb[(r - N_POL - N_TICK)*EMB + c];
    }

    // layernorm across the 32 lanes of this row-group
    float s = acc;
    #pragma unroll
    for (int m = 16; m >= 1; m >>= 1) s += __shfl_xor(s, m, 32);
    float mu = s * (1.f/32.f);
    float d  = acc - mu;
    float v  = d * d;
    #pragma unroll
    for (int m = 16; m >= 1; m >>= 1) v += __shfl_xor(v, m, 32);
    v *= (1.f/32.f);
    x[r*EMB + c] = d * rsqrtf(v + 1e-5f) * ln_g[c] + ln_b[c];
}

// ---------------------------------------------------------------------------
// K2/K4: edge scatter.  32 lanes per edge; lane c does
//   agg[dst][c] += feat[src][c] * w   (hardware f32 atomic)
// ---------------------------------------------------------------------------
__global__ __launch_bounds__(256) void k_scatter(
    const int* __restrict__ ei, const float* __restrict__ ew,
    const float* __restrict__ feat, float* __restrict__ agg)
{
    int tid = blockIdx.x * 256 + threadIdx.x;
    int e = tid >> 5;
    int c = tid & 31;
    if (e >= N_EDGES) return;
    int src = ei[e];
    int dst = ei[N_EDGES + e];
    float w = ew[e];
    float v = feat[src*EMB + c] * w;
    unsafeAtomicAdd(&agg[dst*EMB + c], v);
}

// ---------------------------------------------------------------------------
// K3: x1 = relu(agg @ w1_rel + b1 + x @ w1_root)   [N,64]
//     z  = x1 @ w2_rel                             [N,32]  (z may alias x)
// One 64-lane wave per row; weights staged in LDS; row broadcast via shfl.
// ---------------------------------------------------------------------------
__global__ __launch_bounds__(256) void k_conv1(
    const float* x, const float* __restrict__ agg,
    const float* __restrict__ w1_rel, const float* __restrict__ b1_rel,
    const float* __restrict__ w1_root, const float* __restrict__ w2_rel,
    float* __restrict__ x1, float* z)
{
    __shared__ float s_rel[32*64];
    __shared__ float s_root[32*64];
    __shared__ float s_w2[64*32];
    __shared__ float s_b1[64];
    for (int i = threadIdx.x; i < 2048; i += 256) {
        s_rel[i]  = w1_rel[i];
        s_root[i] = w1_root[i];
        s_w2[i]   = w2_rel[i];
    }
    if (threadIdx.x < 64) s_b1[threadIdx.x] = b1_rel[threadIdx.x];
    __syncthreads();

    int lane = threadIdx.x & 63;
    int wave = threadIdx.x >> 6;
    int c    = lane & 31;
    int half = lane >> 5;

    for (int r = blockIdx.x*4 + wave; r < N_NODES; r += gridDim.x*4) {
        // lanes 0..31 hold x-row, lanes 32..63 hold agg-row
        float val = (lane < 32) ? x[r*EMB + lane] : agg[r*EMB + (lane - 32)];
        float acc = s_b1[lane];
        #pragma unroll
        for (int k = 0; k < 32; ++k) {
            float xk = __shfl(val, k, 64);
            float ak = __shfl(val, k + 32, 64);
            acc = fmaf(ak, s_rel[k*64 + lane], acc);
            acc = fmaf(xk, s_root[k*64 + lane], acc);
        }
        acc = fmaxf(acc, 0.f);
        x1[r*HID + lane] = acc;

        // z[c] = sum_k x1row[k] * w2_rel[k][c]; split k-range across halves
        float part = 0.f;
        #pragma unroll
        for (int kk = 0; kk < 32; ++kk) {
            int k = half*32 + kk;
            part = fmaf(__shfl(acc, k, 64), s_w2[k*32 + c], part);
        }
        part += __shfl_xor(part, 32, 64);
        if (lane < 32) z[r*EMB + c] = part;
    }
}

// ---------------------------------------------------------------------------
// K5: out = agg2 + b2 + x1 @ w2_root
// ---------------------------------------------------------------------------
__global__ __launch_bounds__(256) void k_conv2(
    const float* __restrict__ x1, const float* __restrict__ agg,
    const float* __restrict__ w2_root, const float* __restrict__ b2_rel,
    float* __restrict__ out)
{
    __shared__ float s_w[64*32];
    for (int i = threadIdx.x; i < 2048; i += 256) s_w[i] = w2_root[i];
    __syncthreads();

    int lane = threadIdx.x & 63;
    int wave = threadIdx.x >> 6;
    int c    = lane & 31;
    int half = lane >> 5;

    for (int r = blockIdx.x*4 + wave; r < N_NODES; r += gridDim.x*4) {
        float v = x1[r*HID + lane];
        float part = 0.f;
        #pragma unroll
        for (int kk = 0; kk < 32; ++kk) {
            int k = half*32 + kk;
            part = fmaf(__shfl(v, k, 64), s_w[k*32 + c], part);
        }
        part += __shfl_xor(part, 32, 64);
        if (lane < 32)
            out[r*OUT_D + c] = part + agg[r*EMB + c] + b2_rel[c];
    }
}

extern "C" void kernel_launch(void* const* d_in, const int* in_sizes, int n_in,
                              void* d_out, int out_size, void* d_ws, size_t ws_size,
                              hipStream_t stream) {
    const float* pol_features = (const float*)d_in[0];
    const int*   state_ids    = (const int*)  d_in[1];
    const int*   sector_ids   = (const int*)  d_in[2];
    const int*   industry_ids = (const int*)  d_in[3];
    const float* comp_extra   = (const float*)d_in[4];
    const int*   edge_index   = (const int*)  d_in[5];
    const float* edge_weight  = (const float*)d_in[6];
    const float* pol_W        = (const float*)d_in[7];
    const float* pol_b        = (const float*)d_in[8];
    const float* state_emb    = (const float*)d_in[9];
    const float* sector_emb   = (const float*)d_in[10];
    const float* industry_emb = (const float*)d_in[11];
    const float* comp_W       = (const float*)d_in[12];
    const float* comp_b       = (const float*)d_in[13];
    const float* comm_emb     = (const float*)d_in[14];
    const float* ln_g         = (const float*)d_in[15];
    const float* ln_b         = (const float*)d_in[16];
    const float* w1_rel       = (const float*)d_in[17];
    const float* b1_rel       = (const float*)d_in[18];
    const float* w1_root      = (const float*)d_in[19];
    const float* w2_rel       = (const float*)d_in[20];
    const float* b2_rel       = (const float*)d_in[21];
    const float* w2_root      = (const float*)d_in[22];

    // workspace layout (floats): x/z [255000*32] | x1 [255000*64] | agg [255000*32]
    float* x   = (float*)d_ws;
    float* x1  = x  + (size_t)N_NODES * EMB;
    float* agg = x1 + (size_t)N_NODES * HID;
    float* out = (float*)d_out;

    hipMemsetAsync(agg, 0, (size_t)N_NODES * EMB * sizeof(float), stream);

    k_embed<<<(N_NODES*32 + 255)/256, 256, 0, stream>>>(
        pol_features, state_ids, sector_ids, industry_ids, comp_extra,
        pol_W, pol_b, state_emb, sector_emb, industry_emb, comp_W, comp_b,
        comm_emb, ln_g, ln_b, x);

    k_scatter<<<(N_EDGES*32)/256, 256, 0, stream>>>(edge_index, edge_weight, x, agg);

    k_conv1<<<4096, 256, 0, stream>>>(x, agg, w1_rel, b1_rel, w1_root, w2_rel,
                                      x1, /*z aliases x*/ x);

    hipMemsetAsync(agg, 0, (size_t)N_NODES * EMB * sizeof(float), stream);

    k_scatter<<<(N_EDGES*32)/256, 256, 0, stream>>>(edge_index, edge_weight,
                                                    /*z*/ x, agg);

    k_conv2<<<4096, 256, 0, stream>>>(x1, agg, w2_root, b2_rel, out);
}

// Round 6
// 1111.614 us; speedup vs baseline: 1.2333x; 1.2333x over previous
//
#include <hip/hip_runtime.h>
#include <hip/hip_bf16.h>

#define N_POL  50000
#define N_TICK 200000
#define N_COMM 5000
#define N_NODES 255000   // N_POL + N_TICK + N_COMM
#define N_EDGES 4000000
#define EMB 32
#define HID 64
#define OUT_D 32

// ---------------------------------------------------------------------------
// K1: fused node embedding + layernorm.  One 32-lane group per node row.
// ---------------------------------------------------------------------------
__global__ __launch_bounds__(256) void k_embed(
    const float* __restrict__ pol_features, const int* __restrict__ state_ids,
    const int* __restrict__ sector_ids, const int* __restrict__ industry_ids,
    const float* __restrict__ comp_extra,
    const float* __restrict__ pol_W, const float* __restrict__ pol_b,
    const float* __restrict__ state_emb, const float* __restrict__ sector_emb,
    const float* __restrict__ industry_emb, const float* __restrict__ comp_W,
    const float* __restrict__ comp_b, const float* __restrict__ comm_emb,
    const float* __restrict__ ln_g, const float* __restrict__ ln_b,
    float* __restrict__ x)
{
    int tid = blockIdx.x * 256 + threadIdx.x;
    int r = tid >> 5;
    int c = tid & 31;
    if (r >= N_NODES) return;

    float acc;
    if (r < N_POL) {
        acc = pol_b[c];
        #pragma unroll
        for (int k = 0; k < 7; ++k)
            acc = fmaf(pol_features[r*7 + k], pol_W[k*EMB + c], acc);
        acc = fmaxf(acc, 0.f);
        acc += state_emb[state_ids[r]*EMB + c];
    } else if (r < N_POL + N_TICK) {
        int i = r - N_POL;
        acc = comp_b[c];
        int sec = sector_ids[i], ind = industry_ids[i];
        #pragma unroll
        for (int k = 0; k < 8; ++k)
            acc = fmaf(sector_emb[sec*8 + k], comp_W[k*EMB + c], acc);
        #pragma unroll
        for (int k = 0; k < 8; ++k)
            acc = fmaf(industry_emb[ind*8 + k], comp_W[(8+k)*EMB + c], acc);
        acc = fmaf(comp_extra[i], comp_W[16*EMB + c], acc);
        acc = fmaxf(acc, 0.f);
    } else {
        acc = comm_emb[(r - N_POL - N_TICK)*EMB + c];
    }

    // layernorm across the 32 lanes of this row-group
    float s = acc;
    #pragma unroll
    for (int m = 16; m >= 1; m >>= 1) s += __shfl_xor(s, m, 32);
    float mu = s * (1.f/32.f);
    float d  = acc - mu;
    float v  = d * d;
    #pragma unroll
    for (int m = 16; m >= 1; m >>= 1) v += __shfl_xor(v, m, 32);
    v *= (1.f/32.f);
    x[r*EMB + c] = d * rsqrtf(v + 1e-5f) * ln_g[c] + ln_b[c];
}

// ---------------------------------------------------------------------------
// CSR build: histogram -> 3-kernel exclusive scan -> fill
// ---------------------------------------------------------------------------
__global__ __launch_bounds__(256) void k_hist(const int* __restrict__ ei,
                                              int* __restrict__ deg)
{
    int e = blockIdx.x * 256 + threadIdx.x;
    if (e >= N_EDGES) return;
    atomicAdd(&deg[ei[N_EDGES + e]], 1);
}

// block b scans deg[b*1024 .. b*1024+1023] (4 elems/thread), writes local
// exclusive prefix into rowptr and the block total into bsum[b].
__global__ __launch_bounds__(256) void k_scan1(const int* __restrict__ deg,
                                               int* __restrict__ rowptr,
                                               int* __restrict__ bsum)
{
    __shared__ int s[256];
    int t = threadIdx.x;
    int base = blockIdx.x * 1024 + t * 4;
    int d0 = (base+0 < N_NODES) ? deg[base+0] : 0;
    int d1 = (base+1 < N_NODES) ? deg[base+1] : 0;
    int d2 = (base+2 < N_NODES) ? deg[base+2] : 0;
    int d3 = (base+3 < N_NODES) ? deg[base+3] : 0;
    int tsum = d0 + d1 + d2 + d3;
    s[t] = tsum;
    __syncthreads();
    for (int off = 1; off < 256; off <<= 1) {
        int v = (t >= off) ? s[t-off] : 0;
        __syncthreads();
        s[t] += v;
        __syncthreads();
    }
    int excl = s[t] - tsum;
    if (base+0 < N_NODES) rowptr[base+0] = excl;
    if (base+1 < N_NODES) rowptr[base+1] = excl + d0;
    if (base+2 < N_NODES) rowptr[base+2] = excl + d0 + d1;
    if (base+3 < N_NODES) rowptr[base+3] = excl + d0 + d1 + d2;
    if (t == 255) bsum[blockIdx.x] = s[255];
}

#define NBLK_SCAN 250   // ceil(255000/1024)

__global__ __launch_bounds__(256) void k_scan2(int* bsum)
{
    __shared__ int s[256];
    int t = threadIdx.x;
    int v = (t < NBLK_SCAN) ? bsum[t] : 0;
    s[t] = v;
    __syncthreads();
    for (int off = 1; off < 256; off <<= 1) {
        int u = (t >= off) ? s[t-off] : 0;
        __syncthreads();
        s[t] += u;
        __syncthreads();
    }
    if (t < NBLK_SCAN) bsum[t] = s[t] - v;   // exclusive
}

__global__ __launch_bounds__(256) void k_scan3(int* __restrict__ rowptr,
                                               const int* __restrict__ bsum)
{
    int i = blockIdx.x * 256 + threadIdx.x;
    if (i < N_NODES) rowptr[i] += bsum[i >> 10];
    if (i == 0) rowptr[N_NODES] = N_EDGES;
}

__global__ __launch_bounds__(256) void k_fill(const int* __restrict__ ei,
                                              const float* __restrict__ ew,
                                              const int* __restrict__ rowptr,
                                              int* __restrict__ cur,
                                              int2* __restrict__ ce)
{
    int e = blockIdx.x * 256 + threadIdx.x;
    if (e >= N_EDGES) return;
    int dst = ei[N_EDGES + e];
    int pos = rowptr[dst] + atomicAdd(&cur[dst], 1);
    ce[pos] = make_int2(ei[e], __float_as_int(ew[e]));
}

// ---------------------------------------------------------------------------
// Pull aggregation: one 32-lane group per dst row; no atomics, no memset.
//   agg[r][c] = sum_{e in CSR[r]} x[src_e][c] * w_e
// 4-way unrolled so 4 independent gathers are in flight.
// ---------------------------------------------------------------------------
__global__ __launch_bounds__(256) void k_agg(const int* __restrict__ rowptr,
                                             const int2* __restrict__ ce,
                                             const float* __restrict__ feat,
                                             float* __restrict__ agg)
{
    int tid = blockIdx.x * 256 + threadIdx.x;
    int r = tid >> 5;
    int c = tid & 31;
    if (r >= N_NODES) return;
    int beg = rowptr[r], end = rowptr[r+1];
    float a0 = 0.f, a1 = 0.f, a2 = 0.f, a3 = 0.f;
    int i = beg;
    for (; i + 4 <= end; i += 4) {
        int2 e0 = ce[i], e1 = ce[i+1], e2 = ce[i+2], e3 = ce[i+3];
        a0 = fmaf(feat[(size_t)e0.x*EMB + c], __int_as_float(e0.y), a0);
        a1 = fmaf(feat[(size_t)e1.x*EMB + c], __int_as_float(e1.y), a1);
        a2 = fmaf(feat[(size_t)e2.x*EMB + c], __int_as_float(e2.y), a2);
        a3 = fmaf(feat[(size_t)e3.x*EMB + c], __int_as_float(e3.y), a3);
    }
    for (; i < end; ++i) {
        int2 e = ce[i];
        a0 = fmaf(feat[(size_t)e.x*EMB + c], __int_as_float(e.y), a0);
    }
    agg[(size_t)r*EMB + c] = (a0 + a1) + (a2 + a3);
}

// ---------------------------------------------------------------------------
// K3: x1 = relu(agg @ w1_rel + b1 + x @ w1_root)   [N,64]
//     z  = x1 @ w2_rel                             [N,32]  (z may alias x)
// ---------------------------------------------------------------------------
__global__ __launch_bounds__(256) void k_conv1(
    const float* x, const float* __restrict__ agg,
    const float* __restrict__ w1_rel, const float* __restrict__ b1_rel,
    const float* __restrict__ w1_root, const float* __restrict__ w2_rel,
    float* __restrict__ x1, float* z)
{
    __shared__ float s_rel[32*64];
    __shared__ float s_root[32*64];
    __shared__ float s_w2[64*32];
    __shared__ float s_b1[64];
    for (int i = threadIdx.x; i < 2048; i += 256) {
        s_rel[i]  = w1_rel[i];
        s_root[i] = w1_root[i];
        s_w2[i]   = w2_rel[i];
    }
    if (threadIdx.x < 64) s_b1[threadIdx.x] = b1_rel[threadIdx.x];
    __syncthreads();

    int lane = threadIdx.x & 63;
    int wave = threadIdx.x >> 6;
    int c    = lane & 31;
    int half = lane >> 5;

    for (int r = blockIdx.x*4 + wave; r < N_NODES; r += gridDim.x*4) {
        float val = (lane < 32) ? x[r*EMB + lane] : agg[r*EMB + (lane - 32)];
        float acc = s_b1[lane];
        #pragma unroll
        for (int k = 0; k < 32; ++k) {
            float xk = __shfl(val, k, 64);
            float ak = __shfl(val, k + 32, 64);
            acc = fmaf(ak, s_rel[k*64 + lane], acc);
            acc = fmaf(xk, s_root[k*64 + lane], acc);
        }
        acc = fmaxf(acc, 0.f);
        x1[r*HID + lane] = acc;

        float part = 0.f;
        #pragma unroll
        for (int kk = 0; kk < 32; ++kk) {
            int k = half*32 + kk;
            part = fmaf(__shfl(acc, k, 64), s_w2[k*32 + c], part);
        }
        part += __shfl_xor(part, 32, 64);
        if (lane < 32) z[r*EMB + c] = part;
    }
}

// ---------------------------------------------------------------------------
// K5: out = agg2 + b2 + x1 @ w2_root
// ---------------------------------------------------------------------------
__global__ __launch_bounds__(256) void k_conv2(
    const float* __restrict__ x1, const float* __restrict__ agg,
    const float* __restrict__ w2_root, const float* __restrict__ b2_rel,
    float* __restrict__ out)
{
    __shared__ float s_w[64*32];
    for (int i = threadIdx.x; i < 2048; i += 256) s_w[i] = w2_root[i];
    __syncthreads();

    int lane = threadIdx.x & 63;
    int wave = threadIdx.x >> 6;
    int c    = lane & 31;
    int half = lane >> 5;

    for (int r = blockIdx.x*4 + wave; r < N_NODES; r += gridDim.x*4) {
        float v = x1[r*HID + lane];
        float part = 0.f;
        #pragma unroll
        for (int kk = 0; kk < 32; ++kk) {
            int k = half*32 + kk;
            part = fmaf(__shfl(v, k, 64), s_w[k*32 + c], part);
        }
        part += __shfl_xor(part, 32, 64);
        if (lane < 32)
            out[r*OUT_D + c] = part + agg[r*EMB + c] + b2_rel[c];
    }
}

extern "C" void kernel_launch(void* const* d_in, const int* in_sizes, int n_in,
                              void* d_out, int out_size, void* d_ws, size_t ws_size,
                              hipStream_t stream) {
    const float* pol_features = (const float*)d_in[0];
    const int*   state_ids    = (const int*)  d_in[1];
    const int*   sector_ids   = (const int*)  d_in[2];
    const int*   industry_ids = (const int*)  d_in[3];
    const float* comp_extra   = (const float*)d_in[4];
    const int*   edge_index   = (const int*)  d_in[5];
    const float* edge_weight  = (const float*)d_in[6];
    const float* pol_W        = (const float*)d_in[7];
    const float* pol_b        = (const float*)d_in[8];
    const float* state_emb    = (const float*)d_in[9];
    const float* sector_emb   = (const float*)d_in[10];
    const float* industry_emb = (const float*)d_in[11];
    const float* comp_W       = (const float*)d_in[12];
    const float* comp_b       = (const float*)d_in[13];
    const float* comm_emb     = (const float*)d_in[14];
    const float* ln_g         = (const float*)d_in[15];
    const float* ln_b         = (const float*)d_in[16];
    const float* w1_rel       = (const float*)d_in[17];
    const float* b1_rel       = (const float*)d_in[18];
    const float* w1_root      = (const float*)d_in[19];
    const float* w2_rel       = (const float*)d_in[20];
    const float* b2_rel       = (const float*)d_in[21];
    const float* w2_root      = (const float*)d_in[22];

    // workspace layout:
    //   x   [N*32] f32  | x1 [N*64] f32 | agg [N*32] f32
    //   ce  [E] int2    | rowptr [N+1+pad] | cur [N+pad] | bsum [256]
    float* x   = (float*)d_ws;
    float* x1  = x  + (size_t)N_NODES * EMB;
    float* agg = x1 + (size_t)N_NODES * HID;
    int2*  ce  = (int2*)(agg + (size_t)N_NODES * EMB);
    int*   rowptr = (int*)(ce + N_EDGES);
    int*   cur    = rowptr + N_NODES + 8;
    int*   bsum   = cur + N_NODES + 8;
    float* out = (float*)d_out;

    // --- node embeddings (independent of CSR build) ---
    k_embed<<<(N_NODES*32 + 255)/256, 256, 0, stream>>>(
        pol_features, state_ids, sector_ids, industry_ids, comp_extra,
        pol_W, pol_b, state_emb, sector_emb, industry_emb, comp_W, comp_b,
        comm_emb, ln_g, ln_b, x);

    // --- CSR build (by dst) ---
    hipMemsetAsync(cur, 0, (size_t)N_NODES * sizeof(int), stream);
    k_hist<<<(N_EDGES + 255)/256, 256, 0, stream>>>(edge_index, cur);
    k_scan1<<<NBLK_SCAN, 256, 0, stream>>>(cur, rowptr, bsum);
    k_scan2<<<1, 256, 0, stream>>>(bsum);
    k_scan3<<<(N_NODES + 255)/256, 256, 0, stream>>>(rowptr, bsum);
    hipMemsetAsync(cur, 0, (size_t)N_NODES * sizeof(int), stream);
    k_fill<<<(N_EDGES + 255)/256, 256, 0, stream>>>(edge_index, edge_weight,
                                                    rowptr, cur, ce);

    // --- conv1: pull-agg + dense ---
    k_agg<<<(N_NODES*32 + 255)/256, 256, 0, stream>>>(rowptr, ce, x, agg);
    k_conv1<<<4096, 256, 0, stream>>>(x, agg, w1_rel, b1_rel, w1_root, w2_rel,
                                      x1, /*z aliases x*/ x);

    // --- conv2: pull-agg on z + dense epilogue ---
    k_agg<<<(N_NODES*32 + 255)/256, 256, 0, stream>>>(rowptr, ce, /*z*/ x, agg);
    k_conv2<<<4096, 256, 0, stream>>>(x1, agg, w2_root, b2_rel, out);
}

// Round 7
// 921.723 us; speedup vs baseline: 1.4874x; 1.2060x over previous
//
#include <hip/hip_runtime.h>
#include <hip/hip_bf16.h>

#define N_POL  50000
#define N_TICK 200000
#define N_COMM 5000
#define N_NODES 255000   // N_POL + N_TICK + N_COMM
#define N_EDGES 4000000
#define EMB 32
#define HID 64
#define OUT_D 32

// ---------------------------------------------------------------------------
// K1: fused node embedding + layernorm.  One 32-lane group per node row.
// ---------------------------------------------------------------------------
__global__ __launch_bounds__(256) void k_embed(
    const float* __restrict__ pol_features, const int* __restrict__ state_ids,
    const int* __restrict__ sector_ids, const int* __restrict__ industry_ids,
    const float* __restrict__ comp_extra,
    const float* __restrict__ pol_W, const float* __restrict__ pol_b,
    const float* __restrict__ state_emb, const float* __restrict__ sector_emb,
    const float* __restrict__ industry_emb, const float* __restrict__ comp_W,
    const float* __restrict__ comp_b, const float* __restrict__ comm_emb,
    const float* __restrict__ ln_g, const float* __restrict__ ln_b,
    float* __restrict__ x)
{
    int tid = blockIdx.x * 256 + threadIdx.x;
    int r = tid >> 5;
    int c = tid & 31;
    if (r >= N_NODES) return;

    float acc;
    if (r < N_POL) {
        acc = pol_b[c];
        #pragma unroll
        for (int k = 0; k < 7; ++k)
            acc = fmaf(pol_features[r*7 + k], pol_W[k*EMB + c], acc);
        acc = fmaxf(acc, 0.f);
        acc += state_emb[state_ids[r]*EMB + c];
    } else if (r < N_POL + N_TICK) {
        int i = r - N_POL;
        acc = comp_b[c];
        int sec = sector_ids[i], ind = industry_ids[i];
        #pragma unroll
        for (int k = 0; k < 8; ++k)
            acc = fmaf(sector_emb[sec*8 + k], comp_W[k*EMB + c], acc);
        #pragma unroll
        for (int k = 0; k < 8; ++k)
            acc = fmaf(industry_emb[ind*8 + k], comp_W[(8+k)*EMB + c], acc);
        acc = fmaf(comp_extra[i], comp_W[16*EMB + c], acc);
        acc = fmaxf(acc, 0.f);
    } else {
        acc = comm_emb[(r - N_POL - N_TICK)*EMB + c];
    }

    // layernorm across the 32 lanes of this row-group
    float s = acc;
    #pragma unroll
    for (int m = 16; m >= 1; m >>= 1) s += __shfl_xor(s, m, 32);
    float mu = s * (1.f/32.f);
    float d  = acc - mu;
    float v  = d * d;
    #pragma unroll
    for (int m = 16; m >= 1; m >>= 1) v += __shfl_xor(v, m, 32);
    v *= (1.f/32.f);
    x[r*EMB + c] = d * rsqrtf(v + 1e-5f) * ln_g[c] + ln_b[c];
}

// ---------------------------------------------------------------------------
// CSR build: histogram -> 3-kernel exclusive scan -> fill
// ---------------------------------------------------------------------------
__global__ __launch_bounds__(256) void k_hist(const int* __restrict__ ei,
                                              int* __restrict__ deg)
{
    int e = blockIdx.x * 256 + threadIdx.x;
    if (e >= N_EDGES) return;
    atomicAdd(&deg[ei[N_EDGES + e]], 1);
}

__global__ __launch_bounds__(256) void k_scan1(const int* __restrict__ deg,
                                               int* __restrict__ rowptr,
                                               int* __restrict__ bsum)
{
    __shared__ int s[256];
    int t = threadIdx.x;
    int base = blockIdx.x * 1024 + t * 4;
    int d0 = (base+0 < N_NODES) ? deg[base+0] : 0;
    int d1 = (base+1 < N_NODES) ? deg[base+1] : 0;
    int d2 = (base+2 < N_NODES) ? deg[base+2] : 0;
    int d3 = (base+3 < N_NODES) ? deg[base+3] : 0;
    int tsum = d0 + d1 + d2 + d3;
    s[t] = tsum;
    __syncthreads();
    for (int off = 1; off < 256; off <<= 1) {
        int v = (t >= off) ? s[t-off] : 0;
        __syncthreads();
        s[t] += v;
        __syncthreads();
    }
    int excl = s[t] - tsum;
    if (base+0 < N_NODES) rowptr[base+0] = excl;
    if (base+1 < N_NODES) rowptr[base+1] = excl + d0;
    if (base+2 < N_NODES) rowptr[base+2] = excl + d0 + d1;
    if (base+3 < N_NODES) rowptr[base+3] = excl + d0 + d1 + d2;
    if (t == 255) bsum[blockIdx.x] = s[255];
}

#define NBLK_SCAN 250   // ceil(255000/1024)

__global__ __launch_bounds__(256) void k_scan2(int* bsum)
{
    __shared__ int s[256];
    int t = threadIdx.x;
    int v = (t < NBLK_SCAN) ? bsum[t] : 0;
    s[t] = v;
    __syncthreads();
    for (int off = 1; off < 256; off <<= 1) {
        int u = (t >= off) ? s[t-off] : 0;
        __syncthreads();
        s[t] += u;
        __syncthreads();
    }
    if (t < NBLK_SCAN) bsum[t] = s[t] - v;   // exclusive
}

__global__ __launch_bounds__(256) void k_scan3(int* __restrict__ rowptr,
                                               const int* __restrict__ bsum)
{
    int i = blockIdx.x * 256 + threadIdx.x;
    if (i < N_NODES) rowptr[i] += bsum[i >> 10];
    if (i == 0) rowptr[N_NODES] = N_EDGES;
}

__global__ __launch_bounds__(256) void k_fill(const int* __restrict__ ei,
                                              const float* __restrict__ ew,
                                              const int* __restrict__ rowptr,
                                              int* __restrict__ cur,
                                              int2* __restrict__ ce)
{
    int e = blockIdx.x * 256 + threadIdx.x;
    if (e >= N_EDGES) return;
    int dst = ei[N_EDGES + e];
    int pos = rowptr[dst] + atomicAdd(&cur[dst], 1);
    ce[pos] = make_int2(ei[e], __float_as_int(ew[e]));
}

// ---------------------------------------------------------------------------
// Pull aggregation: one 32-lane group per dst row; no atomics, no memset.
// ---------------------------------------------------------------------------
__global__ __launch_bounds__(256) void k_agg(const int* __restrict__ rowptr,
                                             const int2* __restrict__ ce,
                                             const float* __restrict__ feat,
                                             float* __restrict__ agg)
{
    int tid = blockIdx.x * 256 + threadIdx.x;
    int r = tid >> 5;
    int c = tid & 31;
    if (r >= N_NODES) return;
    int beg = rowptr[r], end = rowptr[r+1];
    float a0 = 0.f, a1 = 0.f, a2 = 0.f, a3 = 0.f;
    int i = beg;
    for (; i + 4 <= end; i += 4) {
        int2 e0 = ce[i], e1 = ce[i+1], e2 = ce[i+2], e3 = ce[i+3];
        a0 = fmaf(feat[(size_t)e0.x*EMB + c], __int_as_float(e0.y), a0);
        a1 = fmaf(feat[(size_t)e1.x*EMB + c], __int_as_float(e1.y), a1);
        a2 = fmaf(feat[(size_t)e2.x*EMB + c], __int_as_float(e2.y), a2);
        a3 = fmaf(feat[(size_t)e3.x*EMB + c], __int_as_float(e3.y), a3);
    }
    for (; i < end; ++i) {
        int2 e = ce[i];
        a0 = fmaf(feat[(size_t)e.x*EMB + c], __int_as_float(e.y), a0);
    }
    agg[(size_t)r*EMB + c] = (a0 + a1) + (a2 + a3);
}

// ---------------------------------------------------------------------------
// K3: x1 = relu(agg @ w1_rel + b1 + x @ w1_root)   [N,64]
// One wave per row, lane = output column h.  Weight COLUMNS in VGPRs
// (wr[k]=w1_rel[k][lane], wt[k]=w1_root[k][lane]); row vectors loaded as
// wave-uniform float4 broadcasts.  Zero cross-lane ops.
// ---------------------------------------------------------------------------
__global__ __launch_bounds__(256) void k_conv1(
    const float* __restrict__ x, const float* __restrict__ agg,
    const float* __restrict__ w1_rel, const float* __restrict__ b1_rel,
    const float* __restrict__ w1_root,
    float* __restrict__ x1)
{
    int lane = threadIdx.x & 63;
    int wid  = threadIdx.x >> 6;

    float wr[32], wt[32];
    #pragma unroll
    for (int k = 0; k < 32; ++k) {
        wr[k] = w1_rel[k*HID + lane];
        wt[k] = w1_root[k*HID + lane];
    }
    float bias = b1_rel[lane];

    int nw = gridDim.x * 4;
    for (int r0 = blockIdx.x*4 + wid; r0 < N_NODES; r0 += nw) {
        int r = __builtin_amdgcn_readfirstlane(r0);   // wave-uniform row
        const float4* xr = (const float4*)(x   + (size_t)r*EMB);
        const float4* ar = (const float4*)(agg + (size_t)r*EMB);
        float a0 = bias, a1 = 0.f, a2 = 0.f, a3 = 0.f;
        #pragma unroll
        for (int i = 0; i < 8; ++i) {
            float4 xv = xr[i];
            float4 av = ar[i];
            a0 = fmaf(xv.x, wt[4*i+0], a0);  a0 = fmaf(av.x, wr[4*i+0], a0);
            a1 = fmaf(xv.y, wt[4*i+1], a1);  a1 = fmaf(av.y, wr[4*i+1], a1);
            a2 = fmaf(xv.z, wt[4*i+2], a2);  a2 = fmaf(av.z, wr[4*i+2], a2);
            a3 = fmaf(xv.w, wt[4*i+3], a3);  a3 = fmaf(av.w, wr[4*i+3], a3);
        }
        x1[(size_t)r*HID + lane] = fmaxf((a0 + a1) + (a2 + a3), 0.f);
    }
}

// ---------------------------------------------------------------------------
// K3b: z = x1 @ w2_rel   [N,32].  Wave per row; lane = (c, half); each half
// covers 32 of the 64 h-values; one shfl_xor(32) combines.  z may alias x.
// ---------------------------------------------------------------------------
__global__ __launch_bounds__(256) void k_z(
    const float* __restrict__ x1, const float* __restrict__ w2_rel,
    float* __restrict__ z)
{
    int lane = threadIdx.x & 63;
    int wid  = threadIdx.x >> 6;
    int c    = lane & 31;
    int half = lane >> 5;

    float w[32];
    #pragma unroll
    for (int j = 0; j < 32; ++j) w[j] = w2_rel[(half*32 + j)*OUT_D + c];

    int nw = gridDim.x * 4;
    for (int r0 = blockIdx.x*4 + wid; r0 < N_NODES; r0 += nw) {
        int r = __builtin_amdgcn_readfirstlane(r0);
        const float4* xr = (const float4*)(x1 + (size_t)r*HID + half*32);
        float p0 = 0.f, p1 = 0.f, p2 = 0.f, p3 = 0.f;
        #pragma unroll
        for (int i = 0; i < 8; ++i) {
            float4 v = xr[i];
            p0 = fmaf(v.x, w[4*i+0], p0);
            p1 = fmaf(v.y, w[4*i+1], p1);
            p2 = fmaf(v.z, w[4*i+2], p2);
            p3 = fmaf(v.w, w[4*i+3], p3);
        }
        float part = (p0 + p1) + (p2 + p3);
        part += __shfl_xor(part, 32, 64);
        if (lane < 32) z[(size_t)r*EMB + c] = part;
    }
}

// ---------------------------------------------------------------------------
// K5: out = agg2 + b2 + x1 @ w2_root.  Same structure as k_z + epilogue.
// ---------------------------------------------------------------------------
__global__ __launch_bounds__(256) void k_out(
    const float* __restrict__ x1, const float* __restrict__ agg,
    const float* __restrict__ w2_root, const float* __restrict__ b2_rel,
    float* __restrict__ out)
{
    int lane = threadIdx.x & 63;
    int wid  = threadIdx.x >> 6;
    int c    = lane & 31;
    int half = lane >> 5;

    float w[32];
    #pragma unroll
    for (int j = 0; j < 32; ++j) w[j] = w2_root[(half*32 + j)*OUT_D + c];
    float bias = b2_rel[c];

    int nw = gridDim.x * 4;
    for (int r0 = blockIdx.x*4 + wid; r0 < N_NODES; r0 += nw) {
        int r = __builtin_amdgcn_readfirstlane(r0);
        const float4* xr = (const float4*)(x1 + (size_t)r*HID + half*32);
        float p0 = 0.f, p1 = 0.f, p2 = 0.f, p3 = 0.f;
        #pragma unroll
        for (int i = 0; i < 8; ++i) {
            float4 v = xr[i];
            p0 = fmaf(v.x, w[4*i+0], p0);
            p1 = fmaf(v.y, w[4*i+1], p1);
            p2 = fmaf(v.z, w[4*i+2], p2);
            p3 = fmaf(v.w, w[4*i+3], p3);
        }
        float part = (p0 + p1) + (p2 + p3);
        part += __shfl_xor(part, 32, 64);
        if (lane < 32)
            out[(size_t)r*OUT_D + c] = part + agg[(size_t)r*EMB + c] + bias;
    }
}

extern "C" void kernel_launch(void* const* d_in, const int* in_sizes, int n_in,
                              void* d_out, int out_size, void* d_ws, size_t ws_size,
                              hipStream_t stream) {
    const float* pol_features = (const float*)d_in[0];
    const int*   state_ids    = (const int*)  d_in[1];
    const int*   sector_ids   = (const int*)  d_in[2];
    const int*   industry_ids = (const int*)  d_in[3];
    const float* comp_extra   = (const float*)d_in[4];
    const int*   edge_index   = (const int*)  d_in[5];
    const float* edge_weight  = (const float*)d_in[6];
    const float* pol_W        = (const float*)d_in[7];
    const float* pol_b        = (const float*)d_in[8];
    const float* state_emb    = (const float*)d_in[9];
    const float* sector_emb   = (const float*)d_in[10];
    const float* industry_emb = (const float*)d_in[11];
    const float* comp_W       = (const float*)d_in[12];
    const float* comp_b       = (const float*)d_in[13];
    const float* comm_emb     = (const float*)d_in[14];
    const float* ln_g         = (const float*)d_in[15];
    const float* ln_b         = (const float*)d_in[16];
    const float* w1_rel       = (const float*)d_in[17];
    const float* b1_rel       = (const float*)d_in[18];
    const float* w1_root      = (const float*)d_in[19];
    const float* w2_rel       = (const float*)d_in[20];
    const float* b2_rel       = (const float*)d_in[21];
    const float* w2_root      = (const float*)d_in[22];

    // workspace layout:
    //   x/z [N*32] f32 | x1 [N*64] f32 | agg [N*32] f32
    //   ce  [E] int2   | rowptr [N+1+pad] | cur [N+pad] | bsum [256]
    float* x   = (float*)d_ws;
    float* x1  = x  + (size_t)N_NODES * EMB;
    float* agg = x1 + (size_t)N_NODES * HID;
    int2*  ce  = (int2*)(agg + (size_t)N_NODES * EMB);
    int*   rowptr = (int*)(ce + N_EDGES);
    int*   cur    = rowptr + N_NODES + 8;
    int*   bsum   = cur + N_NODES + 8;
    float* out = (float*)d_out;

    // --- node embeddings (independent of CSR build) ---
    k_embed<<<(N_NODES*32 + 255)/256, 256, 0, stream>>>(
        pol_features, state_ids, sector_ids, industry_ids, comp_extra,
        pol_W, pol_b, state_emb, sector_emb, industry_emb, comp_W, comp_b,
        comm_emb, ln_g, ln_b, x);

    // --- CSR build (by dst) ---
    hipMemsetAsync(cur, 0, (size_t)N_NODES * sizeof(int), stream);
    k_hist<<<(N_EDGES + 255)/256, 256, 0, stream>>>(edge_index, cur);
    k_scan1<<<NBLK_SCAN, 256, 0, stream>>>(cur, rowptr, bsum);
    k_scan2<<<1, 256, 0, stream>>>(bsum);
    k_scan3<<<(N_NODES + 255)/256, 256, 0, stream>>>(rowptr, bsum);
    hipMemsetAsync(cur, 0, (size_t)N_NODES * sizeof(int), stream);
    k_fill<<<(N_EDGES + 255)/256, 256, 0, stream>>>(edge_index, edge_weight,
                                                    rowptr, cur, ce);

    // --- conv1: pull-agg + dense (no cross-lane) ---
    k_agg<<<(N_NODES*32 + 255)/256, 256, 0, stream>>>(rowptr, ce, x, agg);
    k_conv1<<<4096, 256, 0, stream>>>(x, agg, w1_rel, b1_rel, w1_root, x1);
    k_z<<<4096, 256, 0, stream>>>(x1, w2_rel, /*z aliases x*/ x);

    // --- conv2: pull-agg on z + dense epilogue ---
    k_agg<<<(N_NODES*32 + 255)/256, 256, 0, stream>>>(rowptr, ce, /*z*/ x, agg);
    k_out<<<4096, 256, 0, stream>>>(x1, agg, w2_root, b2_rel, out);
}